// Round 2
// baseline (249.721 us; speedup 1.0000x reference)
//
#include <hip/hip_runtime.h>

namespace {
constexpr int kInCh  = 64;
constexpr int kOutCh = 64;
constexpr int kK     = 3;
constexpr int kFanIn = 8;
constexpr int kH     = 1024;
constexpr int kTile  = 128;          // h-positions per tile
constexpr int kRow   = kTile + 8;    // LDS row: 4-float halo each side, float4-aligned
constexpr int kBlk   = 512;          // 8 waves
constexpr int kHB    = kH / kTile;   // 8 h-tiles per batch row
constexpr int kGrid  = 1024;         // 4 blocks/CU resident (LDS-limited); persistent, 4 tiles each
}

struct Tap { int off; float w; };    // off = BYTE offset into sm

// input fake-quant, INTEGER-valued result in [-128,127]. The *0.0625 scale is
// folded into the tap weight (exact: pow2 scale, fmaf fuses the product —
// (w*2^-4)*q is bit-identical to w*(q*2^-4); chain order unchanged).
__device__ __forceinline__ float quant_in_i(float v) {
    float q = rintf(v * 16.0f);
    q = fmaxf(q, -128.0f);
    return fminf(q, 127.0f);
}

// output fake-quant in fp32 (ref conv+quant is fp32; *8 and *0.125 exact pow2)
__device__ __forceinline__ float quant_out(float v) {
    float q = rintf(v * 8.0f);
    q = fmaxf(q, -128.0f);
    q = fminf(q, 127.0f);
    return q * 0.125f;
}

// VERIFIED (prev session round 4 + round 1, absmax=0.0): reference == single fp32
// FMA chain per output in (k-major, ci-minor) tap order. DO NOT change tap
// ordering or accumulation structure.
//
// ROUND 2: persistent 2-phase pipelined blocks. rocprof showed sparse_conv=84us
// with VALUBusy 36% / HBM 43% / Occ 55% — phase-bursty latency-bound (VMEM burst,
// barrier, VALU burst; resident blocks phase-aligned). Fix: grid=1024 (4/CU),
// each block runs 4 tiles, issuing tile t+1's global loads into registers while
// computing tile t (T14 async-stage split). prep_taps folded in (per-wave ballot
// compaction into LDS) — one launch instead of two, no workspace use.
__global__ __launch_bounds__(kBlk, 8) void sparse_conv(
        const float* __restrict__ x,
        const float* __restrict__ weight,
        const float* __restrict__ mask,
        float*       __restrict__ out,
        int nTiles) {
    __shared__ float sm[kInCh * kRow];   // 34,816 B
    __shared__ Tap   tbl[kBlk];          //  4,096 B  -> 38.9 KiB total, 4 blocks/CU

    const int t    = threadIdx.x;
    const int lane = t & 63;
    const int g    = t >> 6;             // wave index = o-group (0..7)

    // ---- build this wave's 64 taps (8 outputs x 8 taps each), rank order
    //      k-major / ci-minor — identical to the verified prep_taps ranking ----
    {
        const unsigned long long low = (1ull << lane) - 1ull;  // lane 63: 0x7fff... (correct)
        #pragma unroll
        for (int oo = 0; oo < 8; ++oo) {
            const int o    = g * 8 + oo;
            const int base = (o * kInCh + lane) * kK;          // OIH storage, lane == ci
            const float m0 = mask[base + 0], m1 = mask[base + 1], m2 = mask[base + 2];
            const float w0 = weight[base + 0], w1 = weight[base + 1], w2 = weight[base + 2];
            const unsigned long long b0 = __ballot(m0 != 0.0f);
            const unsigned long long b1 = __ballot(m1 != 0.0f);
            const unsigned long long b2 = __ballot(m2 != 0.0f);
            const int n0 = __popcll(b0), n1 = __popcll(b1);
            // mask has exactly kFanIn ones per o => ranks cover 0..7 exactly
            if (m0 != 0.0f) { int r = __popcll(b0 & low);
                tbl[o * kFanIn + r].off = (lane * kRow + 3) * 4;
                tbl[o * kFanIn + r].w   = w0 * m0 * 0.0625f; }
            if (m1 != 0.0f) { int r = n0 + __popcll(b1 & low);
                tbl[o * kFanIn + r].off = (lane * kRow + 4) * 4;
                tbl[o * kFanIn + r].w   = w1 * m1 * 0.0625f; }
            if (m2 != 0.0f) { int r = n0 + n1 + __popcll(b2 & low);
                tbl[o * kFanIn + r].off = (lane * kRow + 5) * 4;
                tbl[o * kFanIn + r].w   = w2 * m2 * 0.0625f; }
        }
    }
    __syncthreads();
    // lane l of wave g holds tap (j = l&7) of output (g*8 + l>>3); broadcast via readlane
    const int vOff = tbl[t].off;
    const int vW   = __float_as_int(tbl[t].w);

    // ---- per-thread staging geometry (4 body chunks + halo) ----
    const int tci = t >> 5;      // row within a 16-row chunk group
    const int c4  = t & 31;      // float4 column (32 per row)
    const int i4  = lane << 2;   // byte offset of lane's h within an LDS row

    float4 r0, r1, r2, r3, rh;
    const float4 z4 = make_float4(0.f, 0.f, 0.f, 0.f);

#define ISSUE_LOADS(TAU)                                                          \
    {                                                                             \
        const int   n_  = (TAU) >> 3;                                             \
        const int   h0_ = ((TAU) & (kHB - 1)) * kTile;                            \
        const float* p_ = x + ((size_t)n_ * kInCh) * kH + h0_;                    \
        r0 = reinterpret_cast<const float4*>(p_ + (tci     ) * kH)[c4];           \
        r1 = reinterpret_cast<const float4*>(p_ + (tci + 16) * kH)[c4];           \
        r2 = reinterpret_cast<const float4*>(p_ + (tci + 32) * kH)[c4];           \
        r3 = reinterpret_cast<const float4*>(p_ + (tci + 48) * kH)[c4];           \
        if (t < 64) {                                                             \
            rh = (h0_ > 0) ? *reinterpret_cast<const float4*>(p_ + t * kH - 4)    \
                           : z4;                                                  \
        } else if (t < 128) {                                                     \
            rh = (h0_ + kTile < kH)                                               \
                 ? *reinterpret_cast<const float4*>(p_ + (t - 64) * kH + kTile)   \
                 : z4;                                                            \
        }                                                                         \
    }

#define STAGE()                                                                   \
    {                                                                             \
        float4 q_;                                                                \
        q_.x = quant_in_i(r0.x); q_.y = quant_in_i(r0.y);                         \
        q_.z = quant_in_i(r0.z); q_.w = quant_in_i(r0.w);                         \
        reinterpret_cast<float4*>(&sm[(tci     ) * kRow + 4])[c4] = q_;           \
        q_.x = quant_in_i(r1.x); q_.y = quant_in_i(r1.y);                         \
        q_.z = quant_in_i(r1.z); q_.w = quant_in_i(r1.w);                         \
        reinterpret_cast<float4*>(&sm[(tci + 16) * kRow + 4])[c4] = q_;           \
        q_.x = quant_in_i(r2.x); q_.y = quant_in_i(r2.y);                         \
        q_.z = quant_in_i(r2.z); q_.w = quant_in_i(r2.w);                         \
        reinterpret_cast<float4*>(&sm[(tci + 32) * kRow + 4])[c4] = q_;           \
        q_.x = quant_in_i(r3.x); q_.y = quant_in_i(r3.y);                         \
        q_.z = quant_in_i(r3.z); q_.w = quant_in_i(r3.w);                         \
        reinterpret_cast<float4*>(&sm[(tci + 48) * kRow + 4])[c4] = q_;           \
        if (t < 64) {                                                             \
            float4 h_;                                                            \
            h_.x = quant_in_i(rh.x); h_.y = quant_in_i(rh.y);                     \
            h_.z = quant_in_i(rh.z); h_.w = quant_in_i(rh.w);                     \
            *reinterpret_cast<float4*>(&sm[t * kRow]) = h_;                       \
        } else if (t < 128) {                                                     \
            float4 h_;                                                            \
            h_.x = quant_in_i(rh.x); h_.y = quant_in_i(rh.y);                     \
            h_.z = quant_in_i(rh.z); h_.w = quant_in_i(rh.w);                     \
            *reinterpret_cast<float4*>(&sm[(t - 64) * kRow + 4 + kTile]) = h_;    \
        }                                                                         \
    }

    // ---- persistent tile loop: stage -> barrier -> {prefetch next || compute} ----
    int tau = blockIdx.x;
    const int stride = gridDim.x;
    const char* smb = reinterpret_cast<const char*>(sm);

    ISSUE_LOADS(tau);
    while (tau < nTiles) {
        STAGE();                      // implicit vmcnt wait on r0..r3/rh
        __syncthreads();              // tile visible to all waves

        const int nxt = tau + stride;
        if (nxt < nTiles) ISSUE_LOADS(nxt);   // VMEM in flight under compute

        float* __restrict__ outn =
            out + ((size_t)(tau >> 3) * kOutCh) * kH + (tau & (kHB - 1)) * kTile;

        #pragma unroll 2
        for (int oo = 0; oo < 8; ++oo) {
            const int o = g * 8 + oo;
            // Single sequential fp32 FMA chain, j ascending (verified order).
            // Pair {i, i+64} -> ds_read2_b32, stride-1 lanes, conflict-free.
            float acc0 = 0.f, acc1 = 0.f;
            #pragma unroll
            for (int j = 0; j < kFanIn; ++j) {
                const int l   = oo * 8 + j;                               // uniform
                const int off = __builtin_amdgcn_readlane(vOff, l);       // SGPR
                const float w = __int_as_float(__builtin_amdgcn_readlane(vW, l));
                const float a0 = *reinterpret_cast<const float*>(smb + off + i4);
                const float a1 = *reinterpret_cast<const float*>(smb + off + i4 + 256);
                acc0 = fmaf(w, a0, acc0);
                acc1 = fmaf(w, a1, acc1);
            }
            outn[o * kH + lane]      = quant_out(acc0);
            outn[o * kH + lane + 64] = quant_out(acc1);
        }
        __syncthreads();              // all reads of sm done before next STAGE
        tau = nxt;
    }
#undef ISSUE_LOADS
#undef STAGE
}

extern "C" void kernel_launch(void* const* d_in, const int* in_sizes, int n_in,
                              void* d_out, int out_size, void* d_ws, size_t ws_size,
                              hipStream_t stream) {
    const float* x      = (const float*)d_in[0];
    const float* weight = (const float*)d_in[1];
    const float* mask   = (const float*)d_in[2];
    float* out = (float*)d_out;

    const int nBatch = in_sizes[0] / (kInCh * kH);   // 512
    const int nTiles = nBatch * kHB;                 // 4096
    const int grid   = nTiles < kGrid ? nTiles : kGrid;

    sparse_conv<<<grid, kBlk, 0, stream>>>(x, weight, mask, out, nTiles);
}